// Round 1
// baseline (203.187 us; speedup 1.0000x reference)
//
#include <hip/hip_runtime.h>
#include <hip/hip_bf16.h>

#define HW 3136
#define HH 56
#define WW 56
#define BB 4
#define CC 256
#define HD 128

// attention tile geometry
#define TH 4
#define TW 8
#define WR 8    // TH+4
#define WC 12   // TW+4
#define WPX 96  // WR*WC
#define KS2 136 // ushorts per window pixel: 128 + 8 pad (272B stride: 16B-aligned, even bank spread)

// MFMA GEMM geometry: 128x128 tile, BK=64, LDS row = 64 bf16 + pad -> 72 (144 B)
#define ASTR 72

typedef __attribute__((ext_vector_type(8))) short bf16x8;
typedef __attribute__((ext_vector_type(4))) float f32x4;

__device__ __forceinline__ unsigned short f2bf(float f) {
    unsigned int u; __builtin_memcpy(&u, &f, 4);
    unsigned int r = u + 0x7FFFu + ((u >> 16) & 1u);   // RNE
    return (unsigned short)(r >> 16);
}
__device__ __forceinline__ float bflo(unsigned int u) {
    unsigned int x = u << 16; float f; __builtin_memcpy(&f, &x, 4); return f;
}
__device__ __forceinline__ float bfhi(unsigned int u) {
    unsigned int x = u & 0xFFFF0000u; float f; __builtin_memcpy(&f, &x, 4); return f;
}
__device__ __forceinline__ void unpk8(uint4 u, float* f) {
    f[0] = bflo(u.x); f[1] = bfhi(u.x); f[2] = bflo(u.y); f[3] = bfhi(u.y);
    f[4] = bflo(u.z); f[5] = bfhi(u.z); f[6] = bflo(u.w); f[7] = bfhi(u.w);
}

// ---------------- K0: fused conversions ---------------------------------------
// z<4: x [b][c][p] fp32 -> xt [(b*HW+p)][c] bf16  (49x4 tiles per batch)
// z==4: 196 blocks convert Wq/Wk/Wv/Wa/Wse fp32->bf16, zero psum, transpose rel
__global__ __launch_bounds__(256) void cvt_all(
    const float* __restrict__ x,
    const float* __restrict__ Wq, const float* __restrict__ Wk,
    const float* __restrict__ Wv, const float* __restrict__ Wa,
    const float* __restrict__ Wse,
    const float* __restrict__ rel_h, const float* __restrict__ rel_w,
    unsigned short* __restrict__ xt, unsigned short* __restrict__ wb,
    float* __restrict__ psum, float* __restrict__ relws)
{
    int t = threadIdx.x;
    if (blockIdx.z == 4) {
        int bid = blockIdx.y * 49 + blockIdx.x;   // 0..195
        if (bid == 0 && t < 64) psum[t] = 0.f;
        if (bid == 1 && t < 128) {
#pragma unroll
            for (int tt = 0; tt < 5; tt++) {
                relws[tt * 128 + t]       = rel_h[t * 5 + tt];
                relws[640 + tt * 128 + t] = rel_w[t * 5 + tt];
            }
        }
        for (int chunk = bid; chunk < 260; chunk += 196) {
            int wsel, off;
            if (chunk < 256) { wsel = chunk >> 6; off = (chunk & 63) * 1024 + t * 4; }
            else             { wsel = 4;          off = (chunk - 256) * 1024 + t * 4; }
            const float* s = (wsel == 0) ? Wq : (wsel == 1) ? Wk :
                             (wsel == 2) ? Wv : (wsel == 3) ? Wa : Wse;
            float4 f = *(const float4*)(s + off);
            uint2 pk;
            pk.x = (unsigned int)f2bf(f.x) | ((unsigned int)f2bf(f.y) << 16);
            pk.y = (unsigned int)f2bf(f.z) | ((unsigned int)f2bf(f.w) << 16);
            *(uint2*)(wb + (size_t)wsel * 65536 + off) = pk;
        }
        return;
    }
    int b = blockIdx.z;
    int c0 = blockIdx.y * 64;
    int p0 = blockIdx.x * 64;
    __shared__ float tile[64][65];   // [channel][pixel]
    int p4 = t & 15, cl = t >> 4;
    const float* xb = x + ((size_t)b * CC + c0) * HW + p0;
#pragma unroll
    for (int i = 0; i < 4; i++) {
        int c = cl + 16 * i;
        float4 f = *(const float4*)(xb + (size_t)c * HW + p4 * 4);
        tile[c][p4 * 4 + 0] = f.x; tile[c][p4 * 4 + 1] = f.y;
        tile[c][p4 * 4 + 2] = f.z; tile[c][p4 * 4 + 3] = f.w;
    }
    __syncthreads();
    int c2 = t & 31, pl = t >> 5;
    unsigned short* xo = xt + ((size_t)b * HW + p0) * CC + c0;
#pragma unroll
    for (int i = 0; i < 8; i++) {
        int p = pl + 8 * i;
        float a = tile[2 * c2][p], bb = tile[2 * c2 + 1][p];
        unsigned int pk = (unsigned int)f2bf(a) | ((unsigned int)f2bf(bb) << 16);
        *(unsigned int*)(xo + (size_t)p * CC + 2 * c2) = pk;
    }
}

// ---------------- K1: qkv via MFMA bf16, outputs bf16 [(b*HW+p)][o] ----------
__global__ __launch_bounds__(256) void qkv_mfma(
    const unsigned short* __restrict__ xt, const unsigned short* __restrict__ wqkv,
    unsigned short* __restrict__ q_ws, unsigned short* __restrict__ k_ws,
    unsigned short* __restrict__ v_ws)
{
    int wsel = blockIdx.z;
    unsigned short* outp = (wsel == 0) ? q_ws : ((wsel == 1) ? k_ws : v_ws);
    int gp0 = blockIdx.x * 128, o0 = blockIdx.y * 128;

    __shared__ unsigned short As[128 * ASTR];
    __shared__ unsigned short Bs[128 * ASTR];
    const unsigned short* xb = xt + (size_t)gp0 * CC;
    const unsigned short* wbp = wqkv + (size_t)wsel * 65536 + (size_t)o0 * CC;

    int t = threadIdx.x;
    int wave = t >> 6, lane = t & 63;
    int mo = (wave & 1) * 64, no = (wave >> 1) * 64;
    int lm = lane & 15, lq = lane >> 4;
    int sr = t >> 3, sc = t & 7;

    f32x4 acc[4][4];
#pragma unroll
    for (int i = 0; i < 4; i++)
#pragma unroll
        for (int j = 0; j < 4; j++) acc[i][j] = (f32x4){0.f, 0.f, 0.f, 0.f};

    for (int k0 = 0; k0 < 256; k0 += 64) {
#pragma unroll
        for (int i = 0; i < 4; i++) {
            int r = sr + 32 * i;
            *(uint4*)&As[r * ASTR + sc * 8] = *(const uint4*)(xb + (size_t)r * CC + k0 + sc * 8);
            *(uint4*)&Bs[r * ASTR + sc * 8] = *(const uint4*)(wbp + (size_t)r * CC + k0 + sc * 8);
        }
        __syncthreads();
#pragma unroll
        for (int ks = 0; ks < 64; ks += 32) {
            bf16x8 af[4], bfr[4];
#pragma unroll
            for (int i = 0; i < 4; i++)
                af[i] = *(bf16x8*)&As[(mo + 16 * i + lm) * ASTR + ks + lq * 8];
#pragma unroll
            for (int j = 0; j < 4; j++)
                bfr[j] = *(bf16x8*)&Bs[(no + 16 * j + lm) * ASTR + ks + lq * 8];
#pragma unroll
            for (int i = 0; i < 4; i++)
#pragma unroll
                for (int j = 0; j < 4; j++)
                    acc[i][j] = __builtin_amdgcn_mfma_f32_16x16x32_bf16(
                        af[i], bfr[j], acc[i][j], 0, 0, 0);
        }
        __syncthreads();
    }
    unsigned short* ob = outp + (size_t)gp0 * CC + o0;
    bool ev = (lm & 1) == 0;
    int elm = lm & ~1;
#pragma unroll
    for (int i = 0; i < 4; i++)
#pragma unroll
        for (int j = 0; j < 4; j++)
#pragma unroll
            for (int r = 0; r < 4; r++) {
                float v = acc[i][j][r];
                float p = __shfl_xor(v, 1, 64);
                unsigned int pk = ev
                    ? ((unsigned int)f2bf(v) | ((unsigned int)f2bf(p) << 16))
                    : ((unsigned int)f2bf(p) | ((unsigned int)f2bf(v) << 16));
                if (ev == (r < 2)) {
                    int m = mo + 16 * i + lq * 4 + r;
                    int n = no + 16 * j + elm;
                    *(unsigned int*)(ob + (size_t)m * CC + n) = pk;
                }
            }
}

// ---------------- K3: agg via MFMA bf16 (ao bf16 in); BN1+ReLU / BN2 fused ---
__global__ __launch_bounds__(256) void agg_mfma(
    const unsigned short* __restrict__ ao, const unsigned short* __restrict__ wagg,
    const float* __restrict__ g1, const float* __restrict__ b1,
    const float* __restrict__ m1, const float* __restrict__ v1,
    const float* __restrict__ g2, const float* __restrict__ b2,
    const float* __restrict__ m2, const float* __restrict__ v2,
    float* __restrict__ y2)
{
    int gp0 = blockIdx.x * 128, o0 = blockIdx.y * 128;

    __shared__ unsigned short As[128 * ASTR];
    __shared__ unsigned short Bs[128 * ASTR];
    __shared__ float s1[256], o1[256], s2[256], o2[256];

    int t = threadIdx.x;
    {
        float sc1 = g1[t] * rsqrtf(v1[t] + 1e-5f);
        s1[t] = sc1; o1[t] = b1[t] - m1[t] * sc1;
        float sc2 = g2[t] * rsqrtf(v2[t] + 1e-5f);
        s2[t] = sc2; o2[t] = b2[t] - m2[t] * sc2;
    }

    const unsigned short* aob = ao + (size_t)gp0 * CC;
    const unsigned short* wbp = wagg + (size_t)o0 * CC;

    int wave = t >> 6, lane = t & 63;
    int mo = (wave & 1) * 64, no = (wave >> 1) * 64;
    int lm = lane & 15, lq = lane >> 4;
    int sr = t >> 3, sc = t & 7;

    f32x4 acc[4][4];
#pragma unroll
    for (int i = 0; i < 4; i++)
#pragma unroll
        for (int j = 0; j < 4; j++) acc[i][j] = (f32x4){0.f, 0.f, 0.f, 0.f};

    __syncthreads();

    for (int k0 = 0; k0 < 256; k0 += 64) {
#pragma unroll
        for (int i = 0; i < 4; i++) {
            int r = sr + 32 * i;
            int cb = k0 + sc * 8;
            uint4 u = *(const uint4*)(aob + (size_t)r * CC + cb);
            float e[8] = {bflo(u.x), bfhi(u.x), bflo(u.y), bfhi(u.y),
                          bflo(u.z), bfhi(u.z), bflo(u.w), bfhi(u.w)};
            unsigned short pk[8];
#pragma unroll
            for (int uu = 0; uu < 8; uu++) {
                float vv = fmaxf(e[uu] * s1[cb + uu] + o1[cb + uu], 0.f);
                pk[uu] = f2bf(vv);
            }
            *(uint4*)&As[r * ASTR + sc * 8] = *(uint4*)pk;
            *(uint4*)&Bs[r * ASTR + sc * 8] = *(const uint4*)(wbp + (size_t)r * CC + k0 + sc * 8);
        }
        __syncthreads();
#pragma unroll
        for (int ks = 0; ks < 64; ks += 32) {
            bf16x8 af[4], bfr[4];
#pragma unroll
            for (int i = 0; i < 4; i++)
                af[i] = *(bf16x8*)&As[(mo + 16 * i + lm) * ASTR + ks + lq * 8];
#pragma unroll
            for (int j = 0; j < 4; j++)
                bfr[j] = *(bf16x8*)&Bs[(no + 16 * j + lm) * ASTR + ks + lq * 8];
#pragma unroll
            for (int i = 0; i < 4; i++)
#pragma unroll
                for (int j = 0; j < 4; j++)
                    acc[i][j] = __builtin_amdgcn_mfma_f32_16x16x32_bf16(
                        af[i], bfr[j], acc[i][j], 0, 0, 0);
        }
        __syncthreads();
    }
    float* yb = y2 + (size_t)gp0 * CC + o0;
#pragma unroll
    for (int i = 0; i < 4; i++)
#pragma unroll
        for (int j = 0; j < 4; j++)
#pragma unroll
            for (int r = 0; r < 4; r++) {
                int m = mo + 16 * i + lq * 4 + r;
                int n = no + 16 * j + lm;
                yb[(size_t)m * CC + n] = acc[i][j][r] * s2[o0 + n] + o2[o0 + n];
            }
}

// ---------------- K2: local attention, bf16 LDS, single staging pass ---------
// 8 lanes/pixel, 16 contiguous channels/lane. k+v staged up-front (raw uint4
// copies, no unpack), ONE barrier total. rel read from global (L1-resident).
__global__ __launch_bounds__(256) void attn_kernel(
    const unsigned short* __restrict__ q_ws, const unsigned short* __restrict__ k_ws,
    const unsigned short* __restrict__ v_ws,
    const float* __restrict__ relws,
    unsigned short* __restrict__ ao_ws)
{
    __shared__ unsigned short kwin[WPX * KS2];   // 26112 B
    __shared__ unsigned short vwin[WPX * KS2];   // 26112 B  (total 52.2 KB -> 3 blk/CU)

    int t = threadIdx.x;
    int tile = blockIdx.x;
    int n = blockIdx.y;
    int b = blockIdx.z;
    int tr = tile / 7, tc = tile - tr * 7;
    int h0 = tr * TH, w0 = tc * TW;
    const size_t base = (size_t)b * HW * CC + n * HD;
    const float* relp = relws + n * 640;

    {   // stage k AND v as bf16 (no conversion; 16B per lane per buffer)
        int c8 = t & 15, pw0 = t >> 4;
#pragma unroll
        for (int it = 0; it < 6; it++) {
            int pw = pw0 + it * 16;
            int wr = pw / 12, wc = pw - wr * 12;
            int gh = h0 + wr - 2, gw = w0 + wc - 2;
            uint4 uk = make_uint4(0u, 0u, 0u, 0u);
            uint4 uv = make_uint4(0u, 0u, 0u, 0u);
            if (gh >= 0 && gh < HH && gw >= 0 && gw < WW) {
                size_t off = base + (size_t)(gh * WW + gw) * CC + c8 * 8;
                uk = *(const uint4*)(k_ws + off);
                uv = *(const uint4*)(v_ws + off);
            }
            *(uint4*)&kwin[pw * KS2 + c8 * 8] = uk;
            *(uint4*)&vwin[pw * KS2 + c8 * 8] = uv;
        }
    }

    int px = t >> 3, c4g = t & 7;            // pixel 0..31, 16-ch group 0..7
    int pr = px >> 3, pc = px & 7;           // pr == wave id
    int ghp = h0 + pr, gwp = w0 + pc;
    const size_t pbase = base + (size_t)(ghp * WW + gwp) * CC;

    float qf[16];
    {
        uint4 u0 = *(const uint4*)(q_ws + pbase + c4g * 16);
        uint4 u1 = *(const uint4*)(q_ws + pbase + c4g * 16 + 8);
        unpk8(u0, qf); unpk8(u1, qf + 8);
    }

    // q . rel  (global reads, L1-hot: 2.5 KB table shared by all blocks)
    float acc[30];
#pragma unroll
    for (int tt = 0; tt < 5; tt++) {
        float s = 0.f;
#pragma unroll
        for (int j = 0; j < 4; j++) {
            float4 r4 = *(const float4*)(relp + tt * 128 + c4g * 16 + j * 4);
            s += qf[j * 4 + 0] * r4.x + qf[j * 4 + 1] * r4.y
               + qf[j * 4 + 2] * r4.z + qf[j * 4 + 3] * r4.w;
        }
        acc[25 + tt] = s;
    }

    __syncthreads();   // staging complete; only barrier in kernel

    // scores: q . k  (2x ds_read_b128 per tap)
#pragma unroll
    for (int tt = 0; tt < 25; tt++) {
        int di = tt / 5, dj = tt - 5 * di;
        const unsigned short* kp = &kwin[((pr + di) * WC + pc + dj) * KS2 + c4g * 16];
        float kf[16];
        unpk8(*(const uint4*)kp, kf);
        unpk8(*(const uint4*)(kp + 8), kf + 8);
        float s = 0.f;
#pragma unroll
        for (int c = 0; c < 16; c++) s += qf[c] * kf[c];
        acc[tt] = s;
    }

    // reduce the 30 partials over the 8 lanes of this pixel
#pragma unroll
    for (int tt = 0; tt < 30; tt++) {
#pragma unroll
        for (int m = 1; m < 8; m <<= 1)
            acc[tt] += __shfl_xor(acc[tt], m, 64);
    }

    // register softmax (8 lanes of a pixel hold identical sums)
    {
        const float inv = 0.08838834764831845f;
        float mx = -1e30f;
#pragma unroll
        for (int tt = 0; tt < 25; tt++) {
            int di = tt / 5, dj = tt - 5 * (tt / 5);
            acc[tt] = (acc[tt] + ((n == 0) ? acc[25 + di] : acc[25 + dj])) * inv;
            mx = fmaxf(mx, acc[tt]);
        }
        float sum = 0.f;
#pragma unroll
        for (int tt = 0; tt < 25; tt++) { acc[tt] = __expf(acc[tt] - mx); sum += acc[tt]; }
        float rs = 1.f / sum;
#pragma unroll
        for (int tt = 0; tt < 25; tt++) acc[tt] *= rs;
    }

    // PV: v already resident (no barrier, no restage)
    float oacc[16];
#pragma unroll
    for (int c = 0; c < 16; c++) oacc[c] = 0.f;
#pragma unroll
    for (int tt = 0; tt < 25; tt++) {
        int di = tt / 5, dj = tt - 5 * di;
        const unsigned short* vp = &vwin[((pr + di) * WC + pc + dj) * KS2 + c4g * 16];
        float vf[16];
        unpk8(*(const uint4*)vp, vf);
        unpk8(*(const uint4*)(vp + 8), vf + 8);
        float a = acc[tt];
#pragma unroll
        for (int c = 0; c < 16; c++) oacc[c] += a * vf[c];
    }

    unsigned short pk[16];
#pragma unroll
    for (int c = 0; c < 16; c++) pk[c] = f2bf(oacc[c]);
    *(uint4*)(ao_ws + pbase + c4g * 16)     = *(uint4*)pk;
    *(uint4*)(ao_ws + pbase + c4g * 16 + 8) = *(uint4*)&pk[8];
}

// ---------------- K4: SE squeeze via MFMA + fused channel-mean ---------------
// 64-thread blocks, one 16-px tile per block -> 784 blocks (3/CU, was 0.77/CU)
__global__ __launch_bounds__(64) void se_in_mfma(
    const float* __restrict__ y2, const unsigned short* __restrict__ wse,
    const float* __restrict__ gin, const float* __restrict__ bin,
    const float* __restrict__ min_, const float* __restrict__ vin,
    float* __restrict__ s_ws, float* __restrict__ psum)
{
    int lane = threadIdx.x;
    int tile = blockIdx.x;                 // 0..783
    int gp0 = tile * 16;
    int b = tile / 196;                    // 196 tiles per batch
    int lm = lane & 15, lq = lane >> 4;

    f32x4 acc = (f32x4){0.f, 0.f, 0.f, 0.f};
    const float* ya = y2 + (size_t)(gp0 + lm) * CC;
#pragma unroll
    for (int k0 = 0; k0 < 256; k0 += 32) {
        int kb = k0 + lq * 8;
        float4 f0 = *(const float4*)(ya + kb);
        float4 f1 = *(const float4*)(ya + kb + 4);
        unsigned short pk[8] = {f2bf(f0.x), f2bf(f0.y), f2bf(f0.z), f2bf(f0.w),
                                f2bf(f1.x), f2bf(f1.y), f2bf(f1.z), f2bf(f1.w)};
        bf16x8 af = *(bf16x8*)pk;
        bf16x8 bf = *(const bf16x8*)(wse + (size_t)lm * CC + kb);
        acc = __builtin_amdgcn_mfma_f32_16x16x32_bf16(af, bf, acc, 0, 0, 0);
    }
    float sc = gin[lm] * rsqrtf(vin[lm] + 1e-5f);
    float off = bin[lm] - min_[lm] * sc;
    float sum4 = 0.f;
#pragma unroll
    for (int r = 0; r < 4; r++) {
        int row = lq * 4 + r;
        float v = fmaxf(acc[r] * sc + off, 0.f);
        s_ws[(size_t)(gp0 + row) * 16 + lm] = v;
        sum4 += v;
    }
    sum4 += __shfl_xor(sum4, 16, 64);
    sum4 += __shfl_xor(sum4, 32, 64);
    if (lane < 16) atomicAdd(&psum[b * 16 + lane], sum4);
}

// ---------------- K5: SE gate + excite conv + BN + fp32 store (NCHW) ---------
__global__ __launch_bounds__(256) void se_out_kernel(
    const float* __restrict__ s_ws, const float* __restrict__ psum,
    const float* __restrict__ fc1, const float* __restrict__ fc2,
    const float* __restrict__ se_Wout,
    const float* __restrict__ gout, const float* __restrict__ bout,
    const float* __restrict__ mout, const float* __restrict__ vout,
    float* __restrict__ out)
{
    int b = blockIdx.y;
    int px0 = blockIdx.x * 32;
    __shared__ float sl[32 * 17];
    __shared__ float wg[256 * 20];
    __shared__ float bo[256];
    __shared__ float gg[16];
    int t = threadIdx.x;

    if (t < 16) {   // gate, redundant per block
        float h = 0.f;
#pragma unroll
        for (int jj = 0; jj < 16; jj++)
            h += (psum[b * 16 + jj] * (1.f / 3136.f)) * fc1[jj];
        h = fmaxf(h, 0.f);
        float z = h * fc2[t];
        gg[t] = 1.f / (1.f + __expf(-z));
    }
    {
        const float* sb = s_ws + (size_t)(b * HW + px0) * 16;
#pragma unroll
        for (int i = 0; i < 2; i++) {
            int idx = t + 256 * i;
            sl[(idx >> 4) * 17 + (idx & 15)] = sb[idx];
        }
    }
    __syncthreads();
    {   // fold weights: wg[o][k] = Wout[o][k] * g[k] * sc2[o]
        float sc = gout[t] * rsqrtf(vout[t] + 1e-5f);
        bo[t] = bout[t] - mout[t] * sc;
        const float* wr = se_Wout + (size_t)t * 16;
#pragma unroll
        for (int k = 0; k < 16; k++)
            wg[t * 20 + k] = wr[k] * gg[k] * sc;
    }
    __syncthreads();

    int px = t & 31, og = t >> 5;          // 8 groups x 32 o
    float4 s0 = *(float4*)&sl[px * 17 + 0];
    float4 s1v = *(float4*)&sl[px * 17 + 4];
    float4 s2v = *(float4*)&sl[px * 17 + 8];
    float4 s3 = *(float4*)&sl[px * 17 + 12];
    float* ob = out + (size_t)b * CC * HW + px0 + px;
#pragma unroll
    for (int oi = 0; oi < 32; oi++) {
        int o = og * 32 + oi;
        float4 w0 = *(float4*)&wg[o * 20 + 0];
        float4 w1 = *(float4*)&wg[o * 20 + 4];
        float4 w2 = *(float4*)&wg[o * 20 + 8];
        float4 w3 = *(float4*)&wg[o * 20 + 12];
        float r = bo[o]
            + s0.x * w0.x + s0.y * w0.y + s0.z * w0.z + s0.w * w0.w
            + s1v.x * w1.x + s1v.y * w1.y + s1v.z * w1.z + s1v.w * w1.w
            + s2v.x * w2.x + s2v.y * w2.y + s2v.z * w2.z + s2v.w * w2.w
            + s3.x * w3.x + s3.y * w3.y + s3.z * w3.z + s3.w * w3.w;
        ob[(size_t)o * HW] = r;
    }
}

extern "C" void kernel_launch(void* const* d_in, const int* in_sizes, int n_in,
                              void* d_out, int out_size, void* d_ws, size_t ws_size,
                              hipStream_t stream) {
    const float* x     = (const float*)d_in[0];
    const float* Wq    = (const float*)d_in[1];
    const float* Wk    = (const float*)d_in[2];
    const float* Wv    = (const float*)d_in[3];
    const float* rel_h = (const float*)d_in[4];
    const float* rel_w = (const float*)d_in[5];
    const float* agg_g1 = (const float*)d_in[6];
    const float* agg_b1 = (const float*)d_in[7];
    const float* agg_m1 = (const float*)d_in[8];
    const float* agg_v1 = (const float*)d_in[9];
    const float* agg_W  = (const float*)d_in[10];
    const float* agg_g2 = (const float*)d_in[11];
    const float* agg_b2 = (const float*)d_in[12];
    const float* agg_m2 = (const float*)d_in[13];
    const float* agg_v2 = (const float*)d_in[14];
    const float* se_Win = (const float*)d_in[15];
    const float* se_g_in = (const float*)d_in[16];
    const float* se_b_in = (const float*)d_in[17];
    const float* se_m_in = (const float*)d_in[18];
    const float* se_v_in = (const float*)d_in[19];
    const float* se_fc1  = (const float*)d_in[20];
    const float* se_fc2  = (const float*)d_in[21];
    const float* se_Wout = (const float*)d_in[22];
    const float* se_g_out = (const float*)d_in[23];
    const float* se_b_out = (const float*)d_in[24];
    const float* se_m_out = (const float*)d_in[25];
    const float* se_v_out = (const float*)d_in[26];

    const size_t NQ = (size_t)BB * HW * CC;   // 3,211,264
    unsigned short* q_ws  = (unsigned short*)d_ws;   // bf16, NQ each
    unsigned short* k_ws  = q_ws + NQ;
    unsigned short* v_ws  = k_ws + NQ;
    unsigned short* ao_ws = v_ws + NQ;
    unsigned short* xt    = ao_ws;                   // alias: xt dead before ao born
    float* y2_ws = (float*)d_ws;                     // alias over q+k (4*NQ bytes)
    float* s_ws  = (float*)(ao_ws + NQ);
    float* psum  = s_ws + (size_t)BB * HW * 16;
    unsigned short* wbf = (unsigned short*)(psum + 64);  // 4x65536 + 4096 bf16
    float* relws = (float*)(wbf + 4 * 65536 + 4096);     // 2 x [5][128] fp32

    cvt_all<<<dim3(49, 4, 5), 256, 0, stream>>>(x, Wq, Wk, Wv, agg_W, se_Win,
                                                rel_h, rel_w, xt, wbf, psum, relws);
    qkv_mfma<<<dim3(98, 2, 3), 256, 0, stream>>>(xt, wbf, q_ws, k_ws, v_ws);
    attn_kernel<<<dim3(98, 2, 4), 256, 0, stream>>>(q_ws, k_ws, v_ws, relws, ao_ws);
    agg_mfma<<<dim3(98, 2), 256, 0, stream>>>(ao_ws, wbf + 3 * 65536,
        agg_g1, agg_b1, agg_m1, agg_v1, agg_g2, agg_b2, agg_m2, agg_v2, y2_ws);
    se_in_mfma<<<dim3(784), 64, 0, stream>>>(y2_ws, wbf + 4 * 65536,
        se_g_in, se_b_in, se_m_in, se_v_in, s_ws, psum);
    se_out_kernel<<<dim3(98, 4), 256, 0, stream>>>(s_ws, psum, se_fc1, se_fc2,
        se_Wout, se_g_out, se_b_out, se_m_out, se_v_out, (float*)d_out);
}